// Round 1
// baseline (1267.008 us; speedup 1.0000x reference)
//
#include <hip/hip_runtime.h>
#include <hip/hip_bf16.h>
#include <math.h>

#define T_TOK 8192
#define DM 1024
#define FF 4096
#define NE 8

typedef short short8 __attribute__((ext_vector_type(8)));
typedef __bf16 bf16x8 __attribute__((ext_vector_type(8)));
typedef float f32x4 __attribute__((ext_vector_type(4)));

__device__ inline ushort f2bf(float f) {
    __hip_bfloat16 h = __float2bfloat16(f);
    return *reinterpret_cast<ushort*>(&h);
}

// ---------------- conversion: x fp32 -> bf16 (same layout) ----------------
__global__ __launch_bounds__(256) void k_cvt_x(const float* __restrict__ in,
                                               ushort* __restrict__ out, int n) {
    int i = (blockIdx.x * 256 + threadIdx.x) * 4;
    if (i >= n) return;
    float4 v = *(const float4*)(in + i);
    ushort4 u;
    u.x = f2bf(v.x); u.y = f2bf(v.y); u.z = f2bf(v.z); u.w = f2bf(v.w);
    *(ushort4*)(out + i) = u;
}

// ------------- transpose+convert: in [E][R][C] fp32 -> out [E][C][R] bf16 -------------
__global__ __launch_bounds__(256) void k_tconv(const float* __restrict__ in,
                                               ushort* __restrict__ out, int R, int C) {
    __shared__ float tile[32][33];
    int e = blockIdx.z;
    const float* I = in + (size_t)e * R * C;
    ushort* O = out + (size_t)e * R * C;
    int tx = threadIdx.x & 31, ty = threadIdx.x >> 5;  // 32x8
    int c0 = blockIdx.x * 32, r0 = blockIdx.y * 32;
#pragma unroll
    for (int i = 0; i < 4; ++i)
        tile[ty + 8 * i][tx] = I[(size_t)(r0 + ty + 8 * i) * C + c0 + tx];
    __syncthreads();
#pragma unroll
    for (int i = 0; i < 4; ++i)
        O[(size_t)(c0 + ty + 8 * i) * R + r0 + tx] = f2bf(tile[tx][ty + 8 * i]);
}

// ---------------- router: wave per token ----------------
__global__ __launch_bounds__(256) void k_router(const float* __restrict__ x,
                                                const float* __restrict__ Wr,
                                                int* __restrict__ topi,
                                                float* __restrict__ topw,
                                                int* __restrict__ cnt) {
    int t = blockIdx.x * 4 + (threadIdx.x >> 6);
    int lane = threadIdx.x & 63;
    const float* xr = x + (size_t)t * DM;
    float xv[16];
#pragma unroll
    for (int i = 0; i < 16; ++i) xv[i] = xr[lane + 64 * i];
    float lg[NE];
#pragma unroll
    for (int e = 0; e < NE; ++e) {
        const float* wr = Wr + e * DM;
        float s = 0.f;
#pragma unroll
        for (int i = 0; i < 16; ++i) s += xv[i] * wr[lane + 64 * i];
#pragma unroll
        for (int o = 32; o > 0; o >>= 1) s += __shfl_xor(s, o, 64);
        lg[e] = s;
    }
    // top-2 (ties -> lower index, matching jax top_k)
    int i1 = 0;
#pragma unroll
    for (int e = 1; e < NE; ++e) if (lg[e] > lg[i1]) i1 = e;
    int i2 = (i1 == 0) ? 1 : 0;
#pragma unroll
    for (int e = 0; e < NE; ++e)
        if (e != i1 && e != i2 && lg[e] > lg[i2]) i2 = e;
    float a = lg[i1], b = lg[i2];
    float w2 = 1.f / (1.f + expf(a - b));  // softmax over the two top logits
    float w1 = 1.f - w2;
    if (lane == 0) {
        topi[t * 2] = i1; topi[t * 2 + 1] = i2;
        topw[t * 2] = w1; topw[t * 2 + 1] = w2;
        atomicAdd(&cnt[i1], 1);
        atomicAdd(&cnt[i2], 1);
    }
}

// ---------------- tiny exclusive scan over 8 experts ----------------
__global__ void k_scan(const int* __restrict__ cnt, int* __restrict__ off) {
    int s = 0;
    for (int e = 0; e < NE; ++e) { off[e] = s; s += cnt[e]; }
    off[NE] = s;
}

// ---------------- scatter token ids into expert buckets ----------------
__global__ __launch_bounds__(256) void k_scatter(const int* __restrict__ topi,
                                                 const float* __restrict__ topw,
                                                 const int* __restrict__ off,
                                                 int* __restrict__ cur,
                                                 int* __restrict__ rowTok,
                                                 float* __restrict__ rowW) {
    int t = blockIdx.x * 256 + threadIdx.x;
    if (t >= T_TOK) return;
#pragma unroll
    for (int k = 0; k < 2; ++k) {
        int e = topi[t * 2 + k];
        int p = atomicAdd(&cur[e], 1);
        int g = off[e] + p;
        rowTok[g] = t;
        rowW[g] = topw[t * 2 + k];
    }
}

// ---------------- grouped GEMM: C = gather(A) @ Wt[e]^T  (Wt stored [E][N][K]) ----
// EPI 0: epilogue = GELU(acc + b1) -> H (bf16)       (A = xbf gathered by token)
// EPI 1: epilogue = atomicAdd(out[tok], w*(acc+b2))  (A = h, direct rows)
template <int EPI>
__global__ __launch_bounds__(256) void k_gemm(const ushort* __restrict__ A,
                                              const ushort* __restrict__ Wt,
                                              const float* __restrict__ bias,
                                              const int* __restrict__ rowTok,
                                              const float* __restrict__ rowW,
                                              const int* __restrict__ cnt,
                                              const int* __restrict__ off,
                                              ushort* __restrict__ H,
                                              float* __restrict__ Out,
                                              int K, int N) {
    const int e = blockIdx.z;
    const int count = cnt[e];
    const int rt = blockIdx.y;
    if (rt * 128 >= count) return;
    const int base = off[e];
    const int n0 = blockIdx.x * 128;
    const int tid = threadIdx.x;

    __shared__ ushort As[128 * 40];  // padded stride 40 elems (80B) vs 32: banks spread
    __shared__ ushort Bs[128 * 40];
    __shared__ int arow[128];
    __shared__ int atok[128];
    __shared__ float arw[128];

    if (tid < 128) {
        int rloc = rt * 128 + tid;
        int rc = rloc < count ? rloc : count - 1;
        int g = base + rc;
        int tk = rowTok[g];
        if (EPI == 0) {
            arow[tid] = tk;      // gather x row by token id
        } else {
            arow[tid] = g;       // h rows are bucket rows directly
            atok[tid] = tk;
            arw[tid] = rowW[g];
        }
    }

    f32x4 acc[4][4];
#pragma unroll
    for (int m = 0; m < 4; ++m)
#pragma unroll
        for (int n = 0; n < 4; ++n) acc[m][n] = (f32x4){0.f, 0.f, 0.f, 0.f};

    const ushort* B = Wt + (size_t)e * N * K + (size_t)n0 * K;
    const int lane = tid & 63, wid = tid >> 6;
    const int wm = (wid >> 1) * 64, wn = (wid & 1) * 64;
    const int lr = lane & 15, kg = (lane >> 4) * 8;

    for (int k0 = 0; k0 < K; k0 += 32) {
        __syncthreads();
#pragma unroll
        for (int p = 0; p < 2; ++p) {
            int c = p * 256 + tid;     // 0..511
            int row = c >> 2;          // 0..127
            int ko = (c & 3) * 8;      // 0,8,16,24
            short8 va = *(const short8*)(A + (size_t)arow[row] * K + k0 + ko);
            *(short8*)&As[row * 40 + ko] = va;
            short8 vb = *(const short8*)(B + (size_t)row * K + k0 + ko);
            *(short8*)&Bs[row * 40 + ko] = vb;
        }
        __syncthreads();
        short8 af[4], bfr[4];
#pragma unroll
        for (int m = 0; m < 4; ++m)
            af[m] = *(const short8*)&As[(wm + m * 16 + lr) * 40 + kg];
#pragma unroll
        for (int n = 0; n < 4; ++n)
            bfr[n] = *(const short8*)&Bs[(wn + n * 16 + lr) * 40 + kg];
#pragma unroll
        for (int m = 0; m < 4; ++m)
#pragma unroll
            for (int n = 0; n < 4; ++n)
                acc[m][n] = __builtin_amdgcn_mfma_f32_16x16x32_bf16(
                    (bf16x8)af[m], (bf16x8)bfr[n], acc[m][n], 0, 0, 0);
    }

    // epilogue: C/D layout col=lane&15, row=(lane>>4)*4+reg  [m89-verified]
    const int rbase = (lane >> 4) * 4;
#pragma unroll
    for (int m = 0; m < 4; ++m) {
#pragma unroll
        for (int n = 0; n < 4; ++n) {
            int col = n0 + wn + n * 16 + lr;
#pragma unroll
            for (int r = 0; r < 4; ++r) {
                int lrow = wm + m * 16 + rbase + r;
                int rloc = rt * 128 + lrow;
                if (rloc < count) {
                    float v = acc[m][n][r];
                    if (EPI == 0) {
                        v += bias[e * FF + col];
                        float g = 0.5f * v * (1.0f + erff(v * 0.70710678118f));
                        H[(size_t)(base + rloc) * FF + col] = f2bf(g);
                    } else {
                        float w = arw[lrow];
                        float o = w * (v + bias[e * DM + col]);
                        atomicAdd(&Out[(size_t)atok[lrow] * DM + col], o);
                    }
                }
            }
        }
    }
}

// ---------------- launch ----------------
extern "C" void kernel_launch(void* const* d_in, const int* in_sizes, int n_in,
                              void* d_out, int out_size, void* d_ws, size_t ws_size,
                              hipStream_t stream) {
    const float* x  = (const float*)d_in[0];
    const float* Wr = (const float*)d_in[1];
    const float* W1 = (const float*)d_in[2];
    const float* b1 = (const float*)d_in[3];
    const float* W2 = (const float*)d_in[4];
    const float* b2 = (const float*)d_in[5];
    float* out = (float*)d_out;

    char* p = (char*)d_ws;
    auto carve = [&](size_t bytes) -> char* {
        char* r = p;
        p += (bytes + 255) & ~(size_t)255;
        return r;
    };
    ushort* xbf   = (ushort*)carve((size_t)T_TOK * DM * 2);
    ushort* w1t   = (ushort*)carve((size_t)NE * FF * DM * 2);
    ushort* w2t   = (ushort*)carve((size_t)NE * DM * FF * 2);
    ushort* h     = (ushort*)carve((size_t)2 * T_TOK * FF * 2);
    int*    topi  = (int*)carve((size_t)T_TOK * 2 * 4);
    float*  topw  = (float*)carve((size_t)T_TOK * 2 * 4);
    int*    rowTok = (int*)carve((size_t)2 * T_TOK * 4);
    float*  rowW   = (float*)carve((size_t)2 * T_TOK * 4);
    int*    cnt   = (int*)carve(64);
    int*    off   = (int*)carve(64);
    int*    cur   = (int*)carve(64);

    hipMemsetAsync(cnt, 0, 64, stream);
    hipMemsetAsync(cur, 0, 64, stream);
    hipMemsetAsync(out, 0, (size_t)out_size * 4, stream);

    k_cvt_x<<<dim3((T_TOK * DM / 4 + 255) / 256), 256, 0, stream>>>(x, xbf, T_TOK * DM);
    k_tconv<<<dim3(FF / 32, DM / 32, NE), 256, 0, stream>>>(W1, w1t, DM, FF);
    k_tconv<<<dim3(DM / 32, FF / 32, NE), 256, 0, stream>>>(W2, w2t, FF, DM);
    k_router<<<dim3(T_TOK / 4), 256, 0, stream>>>(x, Wr, topi, topw, cnt);
    k_scan<<<1, 1, 0, stream>>>(cnt, off);
    k_scatter<<<dim3(T_TOK / 256), 256, 0, stream>>>(topi, topw, off, cur, rowTok, rowW);
    k_gemm<0><<<dim3(FF / 128, 128, NE), 256, 0, stream>>>(
        xbf, w1t, b1, rowTok, rowW, cnt, off, h, nullptr, DM, FF);
    k_gemm<1><<<dim3(DM / 128, 128, NE), 256, 0, stream>>>(
        h, w2t, b2, rowTok, rowW, cnt, off, nullptr, out, FF, DM);
}

// Round 2
// 1128.813 us; speedup vs baseline: 1.1224x; 1.1224x over previous
//
#include <hip/hip_runtime.h>
#include <hip/hip_bf16.h>
#include <math.h>

#define T_TOK 8192
#define DM 1024
#define FF 4096
#define NE 8

typedef short short8 __attribute__((ext_vector_type(8)));
typedef __bf16 bf16x8 __attribute__((ext_vector_type(8)));
typedef float f32x4 __attribute__((ext_vector_type(4)));

__device__ inline ushort f2bf(float f) {
    __hip_bfloat16 h = __float2bfloat16(f);
    return *reinterpret_cast<ushort*>(&h);
}

// async global->LDS DMA, 16B per lane, wave-uniform LDS base (guide §5)
__device__ inline void gload16(const ushort* g, ushort* l) {
    __builtin_amdgcn_global_load_lds(
        (const __attribute__((address_space(1))) void*)g,
        (__attribute__((address_space(3))) void*)l, 16, 0, 0);
}

// ------------- transpose+convert: in [E][R][C] fp32 -> out [E][C][R] bf16 -------------
__global__ __launch_bounds__(256) void k_tconv(const float* __restrict__ in,
                                               ushort* __restrict__ out, int R, int C) {
    __shared__ float tile[32][33];
    int e = blockIdx.z;
    const float* I = in + (size_t)e * R * C;
    ushort* O = out + (size_t)e * R * C;
    int tx = threadIdx.x & 31, ty = threadIdx.x >> 5;  // 32x8
    int c0 = blockIdx.x * 32, r0 = blockIdx.y * 32;
#pragma unroll
    for (int i = 0; i < 4; ++i)
        tile[ty + 8 * i][tx] = I[(size_t)(r0 + ty + 8 * i) * C + c0 + tx];
    __syncthreads();
#pragma unroll
    for (int i = 0; i < 4; ++i)
        O[(size_t)(c0 + ty + 8 * i) * R + r0 + tx] = f2bf(tile[tx][ty + 8 * i]);
}

// ---------------- router: wave per token; also emits x in bf16 ----------------
__global__ __launch_bounds__(256) void k_router(const float* __restrict__ x,
                                                const float* __restrict__ Wr,
                                                ushort* __restrict__ xbf,
                                                int* __restrict__ topi,
                                                float* __restrict__ topw,
                                                int* __restrict__ cnt) {
    int t = blockIdx.x * 4 + (threadIdx.x >> 6);
    int lane = threadIdx.x & 63;
    const float* xr = x + (size_t)t * DM;
    float xv[16];
#pragma unroll
    for (int i = 0; i < 16; ++i) xv[i] = xr[lane + 64 * i];
    // fused x -> bf16 (saves a separate 128MB re-read of x)
#pragma unroll
    for (int i = 0; i < 16; ++i) xbf[(size_t)t * DM + lane + 64 * i] = f2bf(xv[i]);
    float lg[NE];
#pragma unroll
    for (int e = 0; e < NE; ++e) {
        const float* wr = Wr + e * DM;
        float s = 0.f;
#pragma unroll
        for (int i = 0; i < 16; ++i) s += xv[i] * wr[lane + 64 * i];
#pragma unroll
        for (int o = 32; o > 0; o >>= 1) s += __shfl_xor(s, o, 64);
        lg[e] = s;
    }
    // top-2 (ties -> lower index, matching jax top_k)
    int i1 = 0;
#pragma unroll
    for (int e = 1; e < NE; ++e) if (lg[e] > lg[i1]) i1 = e;
    int i2 = (i1 == 0) ? 1 : 0;
#pragma unroll
    for (int e = 0; e < NE; ++e)
        if (e != i1 && e != i2 && lg[e] > lg[i2]) i2 = e;
    float a = lg[i1], b = lg[i2];
    float w2 = 1.f / (1.f + expf(a - b));  // softmax over the two top logits
    float w1 = 1.f - w2;
    if (lane == 0) {
        topi[t * 2] = i1; topi[t * 2 + 1] = i2;
        topw[t * 2] = w1; topw[t * 2 + 1] = w2;
        atomicAdd(&cnt[i1], 1);
        atomicAdd(&cnt[i2], 1);
    }
}

// ---------------- tiny exclusive scan over 8 experts ----------------
__global__ void k_scan(const int* __restrict__ cnt, int* __restrict__ off) {
    int s = 0;
    for (int e = 0; e < NE; ++e) { off[e] = s; s += cnt[e]; }
    off[NE] = s;
}

// ---------------- scatter token ids into expert buckets ----------------
__global__ __launch_bounds__(256) void k_scatter(const int* __restrict__ topi,
                                                 const float* __restrict__ topw,
                                                 const int* __restrict__ off,
                                                 int* __restrict__ cur,
                                                 int* __restrict__ rowTok,
                                                 float* __restrict__ rowW) {
    int t = blockIdx.x * 256 + threadIdx.x;
    if (t >= T_TOK) return;
#pragma unroll
    for (int k = 0; k < 2; ++k) {
        int e = topi[t * 2 + k];
        int p = atomicAdd(&cur[e], 1);
        int g = off[e] + p;
        rowTok[g] = t;
        rowW[g] = topw[t * 2 + k];
    }
}

// ---------------- grouped GEMM (m97 structure): C = gather(A) @ Wt[e]^T ----------------
// Wt stored [E][N][K] bf16. BM=BN=128, BK=64, 4 waves, 16x16x32 MFMA.
// Staging: global_load_lds width 16, linear LDS dest; XOR swizzle slot^=(row&7)
// applied on SOURCE address and on ds_read (both-sides, rule #21).
// EPI 0: H[g][col] = GELU(acc + b1)          (A = xbf gathered by token id)
// EPI 1: atomicAdd(Out[tok][col], w*(acc+b2)) (A = h, bucket rows directly)
template <int EPI>
__global__ __launch_bounds__(256) void k_gemm(const ushort* __restrict__ A,
                                              const ushort* __restrict__ Wt,
                                              const float* __restrict__ bias,
                                              const int* __restrict__ rowTok,
                                              const float* __restrict__ rowW,
                                              const int* __restrict__ cnt,
                                              const int* __restrict__ off,
                                              ushort* __restrict__ H,
                                              float* __restrict__ Out,
                                              int K, int N) {
    const int e = blockIdx.z;
    const int count = cnt[e];
    const int rt = blockIdx.y;
    if (rt * 128 >= count) return;
    const int base = off[e];
    const int n0 = blockIdx.x * 128;
    const int tid = threadIdx.x;

    __shared__ ushort As[128 * 64];  // 16KB, linear (global_load_lds dest)
    __shared__ ushort Bs[128 * 64];  // 16KB
    __shared__ int arow[128];
    __shared__ int atok[128];
    __shared__ float arw[128];

    if (tid < 128) {
        int rloc = rt * 128 + tid;
        int rc = rloc < count ? rloc : count - 1;
        int g = base + rc;
        if (EPI == 0) {
            arow[tid] = rowTok[g];  // gather x row by token id
        } else {
            arow[tid] = g;          // h rows are bucket rows directly
            atok[tid] = rowTok[g];
            arw[tid] = rowW[g];
        }
    }
    __syncthreads();

    const int lane = tid & 63, wid = tid >> 6;
    // staging: chunk c = i*256 + wid*64 + lane; row=c/8, s_phys=c%8 (8 chunks/row)
    // source pre-swizzle: this lane fetches logical slot (s_phys ^ (row&7))
    const ushort* Bbase = Wt + (size_t)e * N * K + (size_t)n0 * K;
    const ushort* pA[4];
    const ushort* pB[4];
#pragma unroll
    for (int i = 0; i < 4; ++i) {
        int row = i * 32 + wid * 8 + (lane >> 3);
        int sp = (lane & 7) ^ (row & 7);
        pA[i] = A + (size_t)arow[row] * K + sp * 8;
        pB[i] = Bbase + (size_t)row * K + sp * 8;
    }

    f32x4 acc[4][4];
#pragma unroll
    for (int m = 0; m < 4; ++m)
#pragma unroll
        for (int n = 0; n < 4; ++n) acc[m][n] = (f32x4){0.f, 0.f, 0.f, 0.f};

    const int wm = (wid >> 1) * 64, wn = (wid & 1) * 64;
    const int lr = lane & 15, kq = lane >> 4;  // kq in 0..3 (8-elem K-group)
    int rA[4], rB[4];
#pragma unroll
    for (int m = 0; m < 4; ++m) rA[m] = wm + m * 16 + lr;
#pragma unroll
    for (int n = 0; n < 4; ++n) rB[n] = wn + n * 16 + lr;

    for (int k0 = 0; k0 < K; k0 += 64) {
#pragma unroll
        for (int i = 0; i < 4; ++i) {
            gload16(pA[i] + k0, &As[(i * 4 + wid) * 512]);
            gload16(pB[i] + k0, &Bs[(i * 4 + wid) * 512]);
        }
        __syncthreads();  // compiler drains vmcnt(0) here -> LDS ready
#pragma unroll
        for (int ks = 0; ks < 2; ++ks) {
            short8 af[4], bf[4];
#pragma unroll
            for (int m = 0; m < 4; ++m)
                af[m] = *(const short8*)&As[rA[m] * 64 + (((ks * 4 + kq) ^ (rA[m] & 7)) * 8)];
#pragma unroll
            for (int n = 0; n < 4; ++n)
                bf[n] = *(const short8*)&Bs[rB[n] * 64 + (((ks * 4 + kq) ^ (rB[n] & 7)) * 8)];
#pragma unroll
            for (int m = 0; m < 4; ++m)
#pragma unroll
                for (int n = 0; n < 4; ++n)
                    acc[m][n] = __builtin_amdgcn_mfma_f32_16x16x32_bf16(
                        (bf16x8)af[m], (bf16x8)bf[n], acc[m][n], 0, 0, 0);
        }
        __syncthreads();  // all waves done reading before next stage overwrites
    }

    // epilogue: C/D layout col=lane&15, row=(lane>>4)*4+reg  [m89-verified]
    const int rbase = kq * 4;
#pragma unroll
    for (int m = 0; m < 4; ++m) {
#pragma unroll
        for (int n = 0; n < 4; ++n) {
            int col = n0 + wn + n * 16 + lr;
#pragma unroll
            for (int r = 0; r < 4; ++r) {
                int lrow = wm + m * 16 + rbase + r;
                int rloc = rt * 128 + lrow;
                if (rloc < count) {
                    float v = acc[m][n][r];
                    if (EPI == 0) {
                        v += bias[e * FF + col];
                        float g = 0.5f * v * (1.0f + erff(v * 0.70710678118f));
                        H[(size_t)(base + rloc) * FF + col] = f2bf(g);
                    } else {
                        float w = arw[lrow];
                        float o = w * (v + bias[e * DM + col]);
                        atomicAdd(&Out[(size_t)atok[lrow] * DM + col], o);
                    }
                }
            }
        }
    }
}

// ---------------- launch ----------------
extern "C" void kernel_launch(void* const* d_in, const int* in_sizes, int n_in,
                              void* d_out, int out_size, void* d_ws, size_t ws_size,
                              hipStream_t stream) {
    const float* x  = (const float*)d_in[0];
    const float* Wr = (const float*)d_in[1];
    const float* W1 = (const float*)d_in[2];
    const float* b1 = (const float*)d_in[3];
    const float* W2 = (const float*)d_in[4];
    const float* b2 = (const float*)d_in[5];
    float* out = (float*)d_out;

    char* p = (char*)d_ws;
    auto carve = [&](size_t bytes) -> char* {
        char* r = p;
        p += (bytes + 255) & ~(size_t)255;
        return r;
    };
    ushort* xbf    = (ushort*)carve((size_t)T_TOK * DM * 2);
    ushort* w1t    = (ushort*)carve((size_t)NE * FF * DM * 2);
    ushort* w2t    = (ushort*)carve((size_t)NE * DM * FF * 2);
    ushort* h      = (ushort*)carve((size_t)2 * T_TOK * FF * 2);
    int*    topi   = (int*)carve((size_t)T_TOK * 2 * 4);
    float*  topw   = (float*)carve((size_t)T_TOK * 2 * 4);
    int*    rowTok = (int*)carve((size_t)2 * T_TOK * 4);
    float*  rowW   = (float*)carve((size_t)2 * T_TOK * 4);
    int*    cnt    = (int*)carve(64);
    int*    off    = (int*)carve(64);
    int*    cur    = (int*)carve(64);

    hipMemsetAsync(cnt, 0, 64, stream);
    hipMemsetAsync(cur, 0, 64, stream);
    hipMemsetAsync(out, 0, (size_t)out_size * 4, stream);

    k_tconv<<<dim3(FF / 32, DM / 32, NE), 256, 0, stream>>>(W1, w1t, DM, FF);
    k_tconv<<<dim3(DM / 32, FF / 32, NE), 256, 0, stream>>>(W2, w2t, FF, DM);
    k_router<<<dim3(T_TOK / 4), 256, 0, stream>>>(x, Wr, xbf, topi, topw, cnt);
    k_scan<<<1, 1, 0, stream>>>(cnt, off);
    k_scatter<<<dim3(T_TOK / 256), 256, 0, stream>>>(topi, topw, off, cur, rowTok, rowW);
    k_gemm<0><<<dim3(FF / 128, 128, NE), 256, 0, stream>>>(
        xbf, w1t, b1, rowTok, rowW, cnt, off, h, nullptr, DM, FF);
    k_gemm<1><<<dim3(DM / 128, 128, NE), 256, 0, stream>>>(
        h, w2t, b2, rowTok, rowW, cnt, off, nullptr, out, FF, DM);
}